// Round 2
// baseline (386.346 us; speedup 1.0000x reference)
//
#include <hip/hip_runtime.h>

#define N_NODES 50000
#define N_EDGES 800000
// IN=HID=64, OUT=16, N_RELS=16, N_BASES=4 (hard-coded below)

// ---------------------------------------------------------------------------
// CSR build: histogram of dst, exclusive scan -> row_ptr, then stable-ish
// scatter of packed edge records (src|ety<<16, norm) into dst-sorted order.
// ---------------------------------------------------------------------------
__global__ __launch_bounds__(256) void k_hist(const int* __restrict__ dst,
                                              int* __restrict__ deg) {
  int e = blockIdx.x * 256 + threadIdx.x;
  if (e < N_EDGES) atomicAdd(&deg[dst[e]], 1);
}

__global__ __launch_bounds__(1024) void k_scan(const int* __restrict__ deg,
                                               int* __restrict__ rowp) {
  __shared__ int wsum[16];
  __shared__ int carry_s;
  const int tid = threadIdx.x, lane = tid & 63, wid = tid >> 6;
  if (tid == 0) carry_s = 0;
  __syncthreads();
  for (int base = 0; base < N_NODES; base += 1024) {
    int i = base + tid;
    int v = (i < N_NODES) ? deg[i] : 0;
    int incl = v;
#pragma unroll
    for (int off = 1; off < 64; off <<= 1) {
      int t = __shfl_up(incl, off, 64);
      if (lane >= off) incl += t;
    }
    if (lane == 63) wsum[wid] = incl;
    __syncthreads();
    if (wid == 0 && lane < 16) {
      int wi = wsum[lane];
#pragma unroll
      for (int off = 1; off < 16; off <<= 1) {
        int t = __shfl_up(wi, off, 64);
        if (lane >= off) wi += t;
      }
      wsum[lane] = wi;  // inclusive scan of wave sums
    }
    __syncthreads();
    int woff = (wid > 0) ? wsum[wid - 1] : 0;
    int total = wsum[15];
    int incl_all = incl + woff + carry_s;
    if (i < N_NODES) rowp[i + 1] = incl_all;
    __syncthreads();
    if (tid == 0) carry_s += total;
    __syncthreads();
  }
  if (tid == 0) rowp[0] = 0;
}

__global__ __launch_bounds__(256) void k_scatter(
    const int* __restrict__ src, const int* __restrict__ dst,
    const int* __restrict__ ety, const float* __restrict__ enorm,
    const int* __restrict__ rowp, int* __restrict__ cursor,
    int2* __restrict__ s_edge) {
  int e = blockIdx.x * 256 + threadIdx.x;
  if (e >= N_EDGES) return;
  int d = dst[e];
  int pos = rowp[d] + atomicAdd(&cursor[d], 1);
  // src < 50000 < 2^16, ety < 16 -> pack into one int
  s_edge[pos] = make_int2(src[e] | (ety[e] << 16), __float_as_int(enorm[e]));
}

// ---------------------------------------------------------------------------
// Gather/aggregate (shared by both layers): one wave per dst node.
// Lane split: eslot = lane>>4 (4 edges in flight), ch = lane&15 (float4 over
// 64 channels). acc[b] per lane; cross-eslot shfl reduction at the end.
// u[d, b, k] = sum_{e->d} norm_e * coef[t_e, b] * x[src_e, k]   (no atomics)
// ---------------------------------------------------------------------------
__global__ __launch_bounds__(256) void k_gather(
    const int* __restrict__ rowp, const int2* __restrict__ s_edge,
    const float4* __restrict__ xv,     // [N][16] float4 = [N][64] floats
    const float4* __restrict__ coefv,  // [16] (coef[t][0..3])
    float4* __restrict__ uv) {         // [N][4][16] float4 = [N][256] floats
  const int node = blockIdx.x * 4 + (threadIdx.x >> 6);
  const int lane = threadIdx.x & 63;
  const int eslot = lane >> 4;
  const int ch = lane & 15;
  const int beg = rowp[node], end = rowp[node + 1];
  float4 a0 = {0, 0, 0, 0}, a1 = {0, 0, 0, 0}, a2 = {0, 0, 0, 0}, a3 = {0, 0, 0, 0};
  for (int j = beg + eslot; j < end; j += 4) {
    int2 rec = s_edge[j];
    int s = rec.x & 0xFFFF;
    float nm = __int_as_float(rec.y);
    float4 c = coefv[(rec.x >> 16) & 15];
    float4 f = xv[s * 16 + ch];
    float w0 = nm * c.x, w1 = nm * c.y, w2 = nm * c.z, w3 = nm * c.w;
    a0.x += w0 * f.x; a0.y += w0 * f.y; a0.z += w0 * f.z; a0.w += w0 * f.w;
    a1.x += w1 * f.x; a1.y += w1 * f.y; a1.z += w1 * f.z; a1.w += w1 * f.w;
    a2.x += w2 * f.x; a2.y += w2 * f.y; a2.z += w2 * f.z; a2.w += w2 * f.w;
    a3.x += w3 * f.x; a3.y += w3 * f.y; a3.z += w3 * f.z; a3.w += w3 * f.w;
  }
  // reduce over eslots: lanes {i, i+16, i+32, i+48} -> lane i
#define RED1(x) x += __shfl_down(x, 32, 64); x += __shfl_down(x, 16, 64)
  RED1(a0.x); RED1(a0.y); RED1(a0.z); RED1(a0.w);
  RED1(a1.x); RED1(a1.y); RED1(a1.z); RED1(a1.w);
  RED1(a2.x); RED1(a2.y); RED1(a2.z); RED1(a2.w);
  RED1(a3.x); RED1(a3.y); RED1(a3.z); RED1(a3.w);
#undef RED1
  if (eslot == 0) {
    float4* up = uv + (size_t)node * 64;
    up[ch] = a0; up[16 + ch] = a1; up[32 + ch] = a2; up[48 + ch] = a3;
  }
}

// ---------------------------------------------------------------------------
// GEMM1: h1[n][o] = relu( sum_q u[n][q] * B1[q][o] + bias1[o] ),  q=256, o=64.
// No LDS: u reads are float4, shared by the 16 lanes of an nsub-group
// (coalesces to one 16B request); B reads are 256B coalesced float4.
// Lane: og = lane&15 (4 outs each), nsub = lane>>4; 4 nodes per nsub.
// ---------------------------------------------------------------------------
__global__ __launch_bounds__(256) void k_gemm1(
    const float4* __restrict__ uv,     // [N][64] float4
    const float4* __restrict__ bv,     // bases1 flat [256][16] float4
    const float4* __restrict__ biasv,  // [16]
    float4* __restrict__ hv) {         // h1 [N][16] float4
  const int wid = threadIdx.x >> 6, lane = threadIdx.x & 63;
  const int og = lane & 15, nsub = lane >> 4;
  const int nbase = (blockIdx.x * 4 + wid) * 16 + nsub * 4;
  int nj[4];
#pragma unroll
  for (int j = 0; j < 4; ++j) {
    int n = nbase + j;
    nj[j] = (n < N_NODES) ? n : (N_NODES - 1);
  }
  float4 acc[4] = {{0, 0, 0, 0}, {0, 0, 0, 0}, {0, 0, 0, 0}, {0, 0, 0, 0}};
  for (int qb = 0; qb < 64; ++qb) {
    float4 b0 = bv[(qb * 4 + 0) * 16 + og];
    float4 b1 = bv[(qb * 4 + 1) * 16 + og];
    float4 b2 = bv[(qb * 4 + 2) * 16 + og];
    float4 b3 = bv[(qb * 4 + 3) * 16 + og];
#pragma unroll
    for (int j = 0; j < 4; ++j) {
      float4 u = uv[(size_t)nj[j] * 64 + qb];
      acc[j].x += u.x * b0.x + u.y * b1.x + u.z * b2.x + u.w * b3.x;
      acc[j].y += u.x * b0.y + u.y * b1.y + u.z * b2.y + u.w * b3.y;
      acc[j].z += u.x * b0.z + u.y * b1.z + u.z * b2.z + u.w * b3.z;
      acc[j].w += u.x * b0.w + u.y * b1.w + u.z * b2.w + u.w * b3.w;
    }
  }
  float4 bs = biasv[og];
#pragma unroll
  for (int j = 0; j < 4; ++j) {
    int n = nbase + j;
    if (n < N_NODES) {
      float4 r;
      r.x = fmaxf(acc[j].x + bs.x, 0.f);
      r.y = fmaxf(acc[j].y + bs.y, 0.f);
      r.z = fmaxf(acc[j].z + bs.z, 0.f);
      r.w = fmaxf(acc[j].w + bs.w, 0.f);
      hv[(size_t)n * 16 + og] = r;
    }
  }
}

// ---------------------------------------------------------------------------
// GEMM2: out[n][o] = relu( sum_q u2[n][q] * B2[q][o] + bias2[o] ), q=256, o=16.
// og = lane&3 (4 outs), nsub = lane>>2 (16 nodes/wave).
// ---------------------------------------------------------------------------
__global__ __launch_bounds__(256) void k_gemm2(
    const float4* __restrict__ uv,     // [N][64] float4
    const float4* __restrict__ bv,     // bases2 flat [256][4] float4
    const float4* __restrict__ biasv,  // [4]
    float4* __restrict__ outv) {       // [N][4] float4
  const int wid = threadIdx.x >> 6, lane = threadIdx.x & 63;
  const int og = lane & 3, nsub = lane >> 2;
  const int n = (blockIdx.x * 4 + wid) * 16 + nsub;
  const int nc = (n < N_NODES) ? n : (N_NODES - 1);
  float4 acc = {0, 0, 0, 0};
  for (int qb = 0; qb < 64; ++qb) {
    float4 b0 = bv[(qb * 4 + 0) * 4 + og];
    float4 b1 = bv[(qb * 4 + 1) * 4 + og];
    float4 b2 = bv[(qb * 4 + 2) * 4 + og];
    float4 b3 = bv[(qb * 4 + 3) * 4 + og];
    float4 u = uv[(size_t)nc * 64 + qb];
    acc.x += u.x * b0.x + u.y * b1.x + u.z * b2.x + u.w * b3.x;
    acc.y += u.x * b0.y + u.y * b1.y + u.z * b2.y + u.w * b3.y;
    acc.z += u.x * b0.z + u.y * b1.z + u.z * b2.z + u.w * b3.z;
    acc.w += u.x * b0.w + u.y * b1.w + u.z * b2.w + u.w * b3.w;
  }
  if (n < N_NODES) {
    float4 bs = biasv[og];
    float4 r;
    r.x = fmaxf(acc.x + bs.x, 0.f);
    r.y = fmaxf(acc.y + bs.y, 0.f);
    r.z = fmaxf(acc.z + bs.z, 0.f);
    r.w = fmaxf(acc.w + bs.w, 0.f);
    outv[(size_t)n * 4 + og] = r;
  }
}

extern "C" void kernel_launch(void* const* d_in, const int* in_sizes, int n_in,
                              void* d_out, int out_size, void* d_ws, size_t ws_size,
                              hipStream_t stream) {
  const float* feats  = (const float*)d_in[0];
  const int*   src    = (const int*)d_in[1];
  const int*   dst    = (const int*)d_in[2];
  const int*   etype  = (const int*)d_in[3];
  const float* enorm  = (const float*)d_in[4];
  const float* bases1 = (const float*)d_in[5];
  const float* coef1  = (const float*)d_in[6];
  const float* bias1  = (const float*)d_in[7];
  const float* bases2 = (const float*)d_in[8];
  const float* coef2  = (const float*)d_in[9];
  const float* bias2  = (const float*)d_in[10];

  // Workspace layout (~71 MB): u (shared between layers) | h1 | deg | cursor
  // | row_ptr | sorted edge records
  float* u12   = (float*)d_ws;                 // 50000*256 floats (51.2 MB)
  float* h1    = u12 + (size_t)N_NODES * 256;  // 50000*64 floats (12.8 MB)
  int*   deg   = (int*)(h1 + (size_t)N_NODES * 64);  // 50000
  int*   cursor = deg + N_NODES;               // 50000 (adjacent: one memset)
  int*   rowp  = cursor + N_NODES;             // 50001
  int2*  s_edge = (int2*)(rowp + N_NODES + 2); // 800000 int2 (8B-aligned: +2)

  hipMemsetAsync(deg, 0, 2 * N_NODES * sizeof(int), stream);  // deg + cursor

  k_hist<<<N_EDGES / 256, 256, 0, stream>>>(dst, deg);
  k_scan<<<1, 1024, 0, stream>>>(deg, rowp);
  k_scatter<<<N_EDGES / 256, 256, 0, stream>>>(src, dst, etype, enorm,
                                               rowp, cursor, s_edge);
  // Layer 1: aggregate feats -> u, then u @ bases1 -> h1 (bias+relu fused)
  k_gather<<<N_NODES / 4, 256, 0, stream>>>(rowp, s_edge, (const float4*)feats,
                                            (const float4*)coef1, (float4*)u12);
  k_gemm1<<<(N_NODES + 63) / 64, 256, 0, stream>>>(
      (const float4*)u12, (const float4*)bases1, (const float4*)bias1,
      (float4*)h1);
  // Layer 2: aggregate h1 -> u, then u @ bases2 -> out (bias+relu fused)
  k_gather<<<N_NODES / 4, 256, 0, stream>>>(rowp, s_edge, (const float4*)h1,
                                            (const float4*)coef2, (float4*)u12);
  k_gemm2<<<(N_NODES + 63) / 64, 256, 0, stream>>>(
      (const float4*)u12, (const float4*)bases2, (const float4*)bias2,
      (float4*)d_out);
}